// Round 9
// baseline (102.526 us; speedup 1.0000x reference)
//
#include <hip/hip_runtime.h>
#include <hip/hip_bf16.h>

#define DIM 1024
#define SEQ 4096
#define NB 4
#define MROWS (NB * SEQ)   // 16384
#define NC 64              // chunks per sequence
#define CL (SEQ / NC)      // 64 L-positions per chunk

// GEMM tiling: 256x128 tile, BK=32, 3 LDS slots (A 16KB + B 8KB each), 2 blocks/CU
#define BM 256
#define BN 128
#define BK 32
#define NTK 32                   // K-tiles: 1024/32
#define SLOTB 24576              // 24 KB per slot
#define GEMM_LDS (3 * SLOTB)     // 72 KB

typedef __attribute__((ext_vector_type(8))) short bf16x8;
typedef __attribute__((ext_vector_type(4))) float f32x4;

static __device__ __forceinline__ unsigned short f2bf(float f) {
    union { float f; unsigned u; } v; v.f = f;
    unsigned r = v.u + 0x7FFF + ((v.u >> 16) & 1);
    return (unsigned short)(r >> 16);
}

static __device__ __forceinline__ float bf2f(unsigned short h) {
    union { unsigned u; float f; } v; v.u = ((unsigned)h) << 16;
    return v.f;
}

static __device__ __forceinline__ void gload_lds16(const void* g, void* l) {
    __builtin_amdgcn_global_load_lds((const __attribute__((address_space(1))) void*)g,
                                     (__attribute__((address_space(3))) void*)l, 16, 0, 0);
}

// ---- convert x and W fp32 -> bf16 (into d_out scratch) ----
__global__ void convert_kernel(const float* __restrict__ x, const float* __restrict__ W,
                               unsigned short* __restrict__ xb, unsigned short* __restrict__ wb) {
    const long long NX4 = (long long)MROWS * DIM / 4;
    const long long NW4 = (long long)DIM * DIM / 4;
    long long t = (long long)blockIdx.x * blockDim.x + threadIdx.x;
    if (t < NX4) {
        float4 v = ((const float4*)x)[t];
        ushort4 o;
        o.x = f2bf(v.x); o.y = f2bf(v.y); o.z = f2bf(v.z); o.w = f2bf(v.w);
        ((ushort4*)xb)[t] = o;
    } else if (t < NX4 + NW4) {
        long long u = t - NX4;
        float4 v = ((const float4*)W)[u];
        ushort4 o;
        o.x = f2bf(v.x); o.y = f2bf(v.y); o.z = f2bf(v.z); o.w = f2bf(v.w);
        ((ushort4*)wb)[u] = o;
    }
}

// LDS rows are 64B with 16B chunks XOR-permuted: stored slot s holds global
// chunk s ^ ((row>>1)&3); staging thread's XOR term equals ((lane>>3)&3).
// Zero-conflict on ds_read verified round 4 (SQ_LDS_BANK_CONFLICT = 0).

// Stage A K-tile (256 rows x 32 bf16 = 16KB) into slot (2 gloads/thread).
static __device__ __forceinline__ void stage_A(const unsigned short* __restrict__ A, char* smem,
                                               int slot, int m0, int ks, int w, int lane) {
    const int c16 = (lane & 3) ^ ((lane >> 3) & 3);
#pragma unroll
    for (int r = 0; r < 2; ++r) {
        int row = r * 128 + w * 16 + (lane >> 2);
        const unsigned short* g = A + (size_t)(m0 + row) * DIM + ks + c16 * 8;
        char* l = smem + (size_t)slot * SLOTB + (r * 128 + w * 16) * 64 + lane * 16;
        gload_lds16(g, l);
    }
}

// Stage B K-tile (128 rows x 32 bf16 = 8KB) into slot at offset 16KB (1 gload).
static __device__ __forceinline__ void stage_B(const unsigned short* __restrict__ Bm, char* smem,
                                               int slot, int n0, int ks, int w, int lane) {
    const int c16 = (lane & 3) ^ ((lane >> 3) & 3);
    int row = w * 16 + (lane >> 2);
    const unsigned short* g = Bm + (size_t)(n0 + row) * DIM + ks + c16 * 8;
    char* l = smem + (size_t)slot * SLOTB + 16384 + (w * 16) * 64 + lane * 16;
    gload_lds16(g, l);
}

// ---- GEMM: V[m][n] = bf16( sum_k A[m][k]*B[n][k] + bias[n] ) ----
// 256x128 tile, 8 waves (2M x 4N: per-wave 128x32 output), 3-slot rotation,
// counted vmcnt(3), one barrier per K-tile, 2 blocks/CU for cross-block overlap.
// MFMA operands swapped (B first) -> lane's 4 acc regs = 4 consecutive output
// columns -> coalesced ushort4 C-store (verified round 8).
__global__ __launch_bounds__(512, 4) void gemm_kernel(const unsigned short* __restrict__ A,
                                                      const unsigned short* __restrict__ Bm,
                                                      const float* __restrict__ bias,
                                                      unsigned short* __restrict__ V) {
    extern __shared__ char smem[];
    const int tid  = threadIdx.x;
    const int lane = tid & 63;
    const int w    = tid >> 6;           // wave 0..7
    const int wr   = (w >> 2) * 128;     // wave row offset (M): 0 or 128
    const int wc   = (w & 3) * 32;       // wave col offset (N): 0..96
    const int rl   = lane & 15;
    const int rh   = lane >> 4;
    const int swz  = (rh ^ ((rl >> 1) & 3)) * 16;  // undo stored XOR permutation
    const int m0   = blockIdx.x * BM;
    const int n0   = blockIdx.y * BN;

    f32x4 acc[8][2];
#pragma unroll
    for (int m = 0; m < 8; ++m)
#pragma unroll
        for (int n = 0; n < 2; ++n)
            acc[m][n] = (f32x4){0.f, 0.f, 0.f, 0.f};

    float4 bv4[2];
#pragma unroll
    for (int nf = 0; nf < 2; ++nf)
        bv4[nf] = *(const float4*)(bias + n0 + wc + nf * 16 + rh * 4);

    // prologue: stage tiles 0 (slot0) and 1 (slot1); 6 loads/thread
    stage_A(A, smem, 0, m0, 0, w, lane);
    stage_B(Bm, smem, 0, n0, 0, w, lane);
    stage_A(A, smem, 1, m0, BK, w, lane);
    stage_B(Bm, smem, 1, n0, BK, w, lane);

#pragma unroll 1
    for (int t = 0; t < NTK; ++t) {
        // tile t resident: drain all but the 3 newest loads (tile t+1's stage)
        asm volatile("s_waitcnt vmcnt(3)" ::: "memory");
        __builtin_amdgcn_s_barrier();
        const int sc = t % 3;
        const int ss = (t + 2) % 3;               // slot freed by iter t-1's reads
        const int kn = ((t + 2) & (NTK - 1)) * BK; // tail wraps into dead slots (safe)
        const char* sb = smem + (size_t)sc * SLOTB;

        // B fragments (2) + A fragments mf 0..3
        bf16x8 bfr[2];
#pragma unroll
        for (int nf = 0; nf < 2; ++nf)
            bfr[nf] = *(const bf16x8*)(sb + 16384 + (wc + nf * 16 + rl) * 64 + swz);
        bf16x8 af[4];
#pragma unroll
        for (int mf = 0; mf < 4; ++mf)
            af[mf] = *(const bf16x8*)(sb + (wr + mf * 16 + rl) * 64 + swz);
        stage_A(A, smem, ss, m0, kn, w, lane);
        __builtin_amdgcn_s_setprio(1);
#pragma unroll
        for (int mf = 0; mf < 4; ++mf)
#pragma unroll
            for (int nf = 0; nf < 2; ++nf)
                acc[mf][nf] = __builtin_amdgcn_mfma_f32_16x16x32_bf16(bfr[nf], af[mf], acc[mf][nf], 0, 0, 0);
        __builtin_amdgcn_s_setprio(0);

        // A fragments mf 4..7 (bfr reused)
#pragma unroll
        for (int mf = 0; mf < 4; ++mf)
            af[mf] = *(const bf16x8*)(sb + (wr + (mf + 4) * 16 + rl) * 64 + swz);
        stage_B(Bm, smem, ss, n0, kn, w, lane);
        __builtin_amdgcn_s_setprio(1);
#pragma unroll
        for (int mf = 0; mf < 4; ++mf)
#pragma unroll
            for (int nf = 0; nf < 2; ++nf)
                acc[mf + 4][nf] = __builtin_amdgcn_mfma_f32_16x16x32_bf16(bfr[nf], af[mf], acc[mf + 4][nf], 0, 0, 0);
        __builtin_amdgcn_s_setprio(0);
    }

    // epilogue: swapped-operand layout -> row = wr+mf*16+rl, cols = wc+nf*16+rh*4+j
#pragma unroll
    for (int mf = 0; mf < 8; ++mf) {
        int grow = m0 + wr + mf * 16 + rl;
#pragma unroll
        for (int nf = 0; nf < 2; ++nf) {
            int gcol0 = n0 + wc + nf * 16 + rh * 4;
            ushort4 o;
            o.x = f2bf(acc[mf][nf][0] + bv4[nf].x);
            o.y = f2bf(acc[mf][nf][1] + bv4[nf].y);
            o.z = f2bf(acc[mf][nf][2] + bv4[nf].z);
            o.w = f2bf(acc[mf][nf][3] + bv4[nf].w);
            *(ushort4*)(V + (size_t)grow * DIM + gcol0) = o;
        }
    }
}

// ---- pass A: per-chunk sums of v*cos, v*sin. 2 e-columns/thread ----
__global__ void passA_kernel(const unsigned short* __restrict__ val, const float* __restrict__ ph,
                             float* __restrict__ pr, float* __restrict__ pi) {
    int t  = blockIdx.x * 256 + threadIdx.x;
    int c  = blockIdx.y;
    int bb = blockIdx.z;
    const ushort2* v = (const ushort2*)val + ((size_t)bb * SEQ + (size_t)c * CL) * (DIM / 2) + t;
    const float2*  p = (const float2*)ph + (size_t)c * CL * (DIM / 2) + t;
    float sr0 = 0.f, si0 = 0.f, sr1 = 0.f, si1 = 0.f;
    for (int l = 0; l < CL; ++l) {
        ushort2 vv = v[(size_t)l * (DIM / 2)];
        float2  pp = p[(size_t)l * (DIM / 2)];
        float v0 = bf2f(vv.x), v1 = bf2f(vv.y);
        float s0, c0, s1, c1;
        __sincosf(pp.x, &s0, &c0);
        __sincosf(pp.y, &s1, &c1);
        sr0 += v0 * c0; si0 += v0 * s0;
        sr1 += v1 * c1; si1 += v1 * s1;
    }
    size_t idx = ((size_t)bb * NC + c) * DIM + 2 * t;
    pr[idx] = sr0; pr[idx + 1] = sr1;
    pi[idx] = si0; pi[idx + 1] = si1;
}

// ---- pass B: exclusive scan of chunk partials over c ----
__global__ void passB_kernel(float* __restrict__ pr, float* __restrict__ pi) {
    int t = blockIdx.x * 256 + threadIdx.x;
    int bb = t >> 10;
    int e  = t & 1023;
    float r = 0.f, im = 0.f;
    for (int c = 0; c < NC; ++c) {
        size_t idx = ((size_t)bb * NC + c) * DIM + e;
        float tr = pr[idx], ti = pi[idx];
        pr[idx] = r; pi[idx] = im;
        r += tr; im += ti;
    }
}

// ---- pass C: running cumsum + retrieval + norm -> fp32 out ----
__global__ void passC_kernel(const unsigned short* __restrict__ val, const float* __restrict__ ph,
                             const float* __restrict__ pr, const float* __restrict__ pi,
                             float* __restrict__ out) {
    int t  = blockIdx.x * 256 + threadIdx.x;
    int c  = blockIdx.y;
    int bb = blockIdx.z;
    size_t base = ((size_t)bb * SEQ + (size_t)c * CL) * (DIM / 2) + t;
    const ushort2* v = (const ushort2*)val + base;
    const float2*  p = (const float2*)ph + (size_t)c * CL * (DIM / 2) + t;
    float2* o = (float2*)out + base;
    size_t pidx = ((size_t)bb * NC + c) * DIM + 2 * t;
    float ar0 = pr[pidx], ar1 = pr[pidx + 1];
    float ai0 = pi[pidx], ai1 = pi[pidx + 1];
    const int l0 = c * CL;
    for (int l = 0; l < CL; ++l) {
        ushort2 vv = v[(size_t)l * (DIM / 2)];
        float2  pp = p[(size_t)l * (DIM / 2)];
        float v0 = bf2f(vv.x), v1 = bf2f(vv.y);
        float s0, c0, s1, c1;
        __sincosf(pp.x, &s0, &c0);
        __sincosf(pp.y, &s1, &c1);
        ar0 += v0 * c0; ai0 += v0 * s0;
        ar1 += v1 * c1; ai1 += v1 * s1;
        float rn = rsqrtf((float)(l0 + l + 1));
        float2 ov;
        ov.x = (ar0 * c0 + ai0 * s0) * rn;
        ov.y = (ar1 * c1 + ai1 * s1) * rn;
        o[(size_t)l * (DIM / 2)] = ov;
    }
}

extern "C" void kernel_launch(void* const* d_in, const int* in_sizes, int n_in,
                              void* d_out, int out_size, void* d_ws, size_t ws_size,
                              hipStream_t stream) {
    const float* x  = (const float*)d_in[0];
    const float* ph = (const float*)d_in[1];
    const float* W  = (const float*)d_in[2];
    const float* b  = (const float*)d_in[3];
    float* out = (float*)d_out;

    // d_out doubles as scratch for bf16 inputs until passC overwrites it
    unsigned short* xb = (unsigned short*)d_out;
    unsigned short* wb = xb + (size_t)MROWS * DIM;

    // ws: vb bf16 32MB | pr 256KB | pi 256KB
    unsigned short* vb = (unsigned short*)d_ws;
    float* pr = (float*)(vb + (size_t)MROWS * DIM);
    float* pi = pr + (size_t)NB * NC * DIM;

    (void)hipFuncSetAttribute((const void*)gemm_kernel,
                              hipFuncAttributeMaxDynamicSharedMemorySize, GEMM_LDS);

    // 1) convert x, W to bf16 (into d_out scratch region)
    {
        long long total4 = (long long)MROWS * DIM / 4 + (long long)DIM * DIM / 4;
        int blocks = (int)((total4 + 255) / 256);
        convert_kernel<<<blocks, 256, 0, stream>>>(x, W, xb, wb);
    }
    // 2) GEMM -> bf16 value into ws (grid 64 x 8 = 512 blocks = 2/CU)
    {
        dim3 grid(MROWS / BM, DIM / BN);
        gemm_kernel<<<grid, 512, GEMM_LDS, stream>>>(xb, wb, b, vb);
    }
    // 3) chunk partial sums
    {
        dim3 grid(DIM / 512, NC, NB);
        passA_kernel<<<grid, 256, 0, stream>>>(vb, ph, pr, pi);
    }
    // 4) scan partials
    passB_kernel<<<16, 256, 0, stream>>>(pr, pi);
    // 5) final cumsum + retrieve + norm -> fp32 d_out
    {
        dim3 grid(DIM / 512, NC, NB);
        passC_kernel<<<grid, 256, 0, stream>>>(vb, ph, pr, pi, out);
    }
}

// Round 10
// 85.784 us; speedup vs baseline: 1.1952x; 1.1952x over previous
//
#include <hip/hip_runtime.h>
#include <hip/hip_bf16.h>

#define DIM 1024
#define SEQ 4096
#define NB 4
#define MROWS (NB * SEQ)   // 16384
#define NC 64              // chunks per sequence
#define CL (SEQ / NC)      // 64 L-positions per chunk

// GEMM tiling: 256x256 tile, BK=32, 3 LDS slots (A fp32 32KB + B bf16 16KB each)
#define BM 256
#define BN 256
#define BK 32
#define NTK 32                   // K-tiles: 1024/32
#define SLOTB 49152              // 48 KB per slot
#define GEMM_LDS (3 * SLOTB)     // 144 KB

typedef __attribute__((ext_vector_type(8))) short bf16x8;
typedef __attribute__((ext_vector_type(4))) float f32x4;

static __device__ __forceinline__ unsigned short f2bf(float f) {
    union { float f; unsigned u; } v; v.f = f;
    unsigned r = v.u + 0x7FFF + ((v.u >> 16) & 1);
    return (unsigned short)(r >> 16);
}

static __device__ __forceinline__ float bf2f(unsigned short h) {
    union { unsigned u; float f; } v; v.u = ((unsigned)h) << 16;
    return v.f;
}

// v_cvt_pk_bf16_f32: RNE, lo=bf16(a) in bits[15:0], hi=bf16(b) in bits[31:16]
static __device__ __forceinline__ unsigned cvtpk(float a, float b) {
    unsigned r;
    asm("v_cvt_pk_bf16_f32 %0, %1, %2" : "=v"(r) : "v"(a), "v"(b));
    return r;
}

static __device__ __forceinline__ void gload_lds16(const void* g, void* l) {
    __builtin_amdgcn_global_load_lds((const __attribute__((address_space(1))) void*)g,
                                     (__attribute__((address_space(3))) void*)l, 16, 0, 0);
}

// ---- convert W fp32 -> bf16 (tiny) ----
__global__ void convertW_kernel(const float* __restrict__ W, unsigned short* __restrict__ wb) {
    int t = blockIdx.x * 256 + threadIdx.x;
    float4 v = ((const float4*)W)[t];
    ushort4 o;
    o.x = f2bf(v.x); o.y = f2bf(v.y); o.z = f2bf(v.z); o.w = f2bf(v.w);
    ((ushort4*)wb)[t] = o;
}

// Stage A K-tile (256 rows x 32 cols fp32 = 32 KB) of tile kt into slot.
// LDS rows 128B = 8 chunks of 16B, stored slot s holds global chunk s^(row&7).
static __device__ __forceinline__ void stage_Af32(const float* __restrict__ srcBase, char* smem,
                                                  int slot, int kt, int w, int lane) {
#pragma unroll
    for (int j = 0; j < 4; ++j) {
        const float* g = srcBase + (size_t)j * 8 * DIM + kt * BK;
        char* l = smem + (size_t)slot * SLOTB + (w * 4 + j) * 1024 + lane * 16;
        gload_lds16(g, l);
    }
}

// Stage B K-tile (256 rows x 32 cols bf16 = 16 KB) into slot at offset 32KB.
static __device__ __forceinline__ void stage_B16(const unsigned short* __restrict__ srcBase, char* smem,
                                                 int slot, int kt, int w, int lane) {
#pragma unroll
    for (int r = 0; r < 2; ++r) {
        const unsigned short* g = srcBase + (size_t)r * 128 * DIM + kt * BK;
        char* l = smem + (size_t)slot * SLOTB + 32768 + (r * 128 + w * 16) * 64 + lane * 16;
        gload_lds16(g, l);
    }
}

// ---- GEMM + fused passA: V = bf16(X@W^T + b); pr/pi[b][c][e] = per-chunk sums ----
// A staged fp32 (x-conversion fused via cvt_pk after ds_read); B staged bf16.
// 3-slot rotation, counted vmcnt(6). Swapped MFMA operands -> lane holds
// row = wr+mf*16+rl, cols = wc+nf*16+rh*4+j (contiguous) -> coalesced stores.
// Epilogue computes per-chunk sums of v*cos/v*sin (chunk = 64 rows, 4/block,
// exactly one writer block per (b,c,e) -> plain stores, no atomics).
__global__ __launch_bounds__(512, 2) void gemm_kernel(const float* __restrict__ X,
                                                      const unsigned short* __restrict__ Bm,
                                                      const float* __restrict__ bias,
                                                      const float* __restrict__ ph,
                                                      unsigned short* __restrict__ V,
                                                      float* __restrict__ pr,
                                                      float* __restrict__ pi) {
    extern __shared__ char smem[];
    const int tid  = threadIdx.x;
    const int lane = tid & 63;
    const int w    = tid >> 6;           // wave 0..7
    const int wr   = (w >> 2) * 128;     // wave row offset (M)
    const int wc   = (w & 3) * 64;       // wave col offset (N)
    const int rl   = lane & 15;
    const int rh   = lane >> 4;
    const int m0   = blockIdx.x * BM;
    const int n0   = blockIdx.y * BN;

    // staging source bases (chunk XOR folded into per-lane global src)
    const float* srcA = X + (size_t)(m0 + w * 32 + (lane >> 3)) * DIM + ((lane & 7) ^ (lane >> 3)) * 4;
    const unsigned short* srcB = Bm + (size_t)(n0 + w * 16 + (lane >> 2)) * DIM
                               + (((lane & 3) ^ ((lane >> 3) & 3)) * 8);

    // read-side offsets
    const int swzB = (rh ^ ((rl >> 1) & 3)) * 16;
    const int aoff0 = (wr + rl) * 128 + (((rh * 2 + 0) ^ (rl & 7)) * 16);
    const int aoff1 = (wr + rl) * 128 + (((rh * 2 + 1) ^ (rl & 7)) * 16);

    f32x4 acc[8][4];
#pragma unroll
    for (int m = 0; m < 8; ++m)
#pragma unroll
        for (int n = 0; n < 4; ++n)
            acc[m][n] = (f32x4){0.f, 0.f, 0.f, 0.f};

    f32x4 bv4[4];
#pragma unroll
    for (int nf = 0; nf < 4; ++nf)
        bv4[nf] = *(const f32x4*)(bias + n0 + wc + nf * 16 + rh * 4);

    // prologue: stage tiles 0 (slot0) and 1 (slot1)
    stage_Af32(srcA, smem, 0, 0, w, lane);
    stage_B16 (srcB, smem, 0, 0, w, lane);
    stage_Af32(srcA, smem, 1, 1, w, lane);
    stage_B16 (srcB, smem, 1, 1, w, lane);

#pragma unroll 1
    for (int t = 0; t < NTK; ++t) {
        asm volatile("s_waitcnt vmcnt(6)" ::: "memory");
        __builtin_amdgcn_s_barrier();
        const int sc = t % 3;
        const int ss = (t + 2) % 3;
        const int kn = (t + 2) & (NTK - 1);
        const char* sb = smem + (size_t)sc * SLOTB;

        bf16x8 bfr[4];
#pragma unroll
        for (int nf = 0; nf < 4; ++nf)
            bfr[nf] = *(const bf16x8*)(sb + 32768 + (wc + nf * 16 + rl) * 64 + swzB);

        bf16x8 af[4];
#pragma unroll
        for (int mf = 0; mf < 4; ++mf) {
            f32x4 q0 = *(const f32x4*)(sb + mf * 2048 + aoff0);
            f32x4 q1 = *(const f32x4*)(sb + mf * 2048 + aoff1);
            union { unsigned u[4]; bf16x8 v; } cv;
            cv.u[0] = cvtpk(q0[0], q0[1]); cv.u[1] = cvtpk(q0[2], q0[3]);
            cv.u[2] = cvtpk(q1[0], q1[1]); cv.u[3] = cvtpk(q1[2], q1[3]);
            af[mf] = cv.v;
        }
        stage_Af32(srcA, smem, ss, kn, w, lane);
        __builtin_amdgcn_s_setprio(1);
#pragma unroll
        for (int mf = 0; mf < 4; ++mf)
#pragma unroll
            for (int nf = 0; nf < 4; ++nf)
                acc[mf][nf] = __builtin_amdgcn_mfma_f32_16x16x32_bf16(bfr[nf], af[mf], acc[mf][nf], 0, 0, 0);
        __builtin_amdgcn_s_setprio(0);

#pragma unroll
        for (int mf = 0; mf < 4; ++mf) {
            f32x4 q0 = *(const f32x4*)(sb + (mf + 4) * 2048 + aoff0);
            f32x4 q1 = *(const f32x4*)(sb + (mf + 4) * 2048 + aoff1);
            union { unsigned u[4]; bf16x8 v; } cv;
            cv.u[0] = cvtpk(q0[0], q0[1]); cv.u[1] = cvtpk(q0[2], q0[3]);
            cv.u[2] = cvtpk(q1[0], q1[1]); cv.u[3] = cvtpk(q1[2], q1[3]);
            af[mf] = cv.v;
        }
        stage_B16(srcB, smem, ss, kn, w, lane);
        __builtin_amdgcn_s_setprio(1);
#pragma unroll
        for (int mf = 0; mf < 4; ++mf)
#pragma unroll
            for (int nf = 0; nf < 4; ++nf)
                acc[mf + 4][nf] = __builtin_amdgcn_mfma_f32_16x16x32_bf16(bfr[nf], af[mf], acc[mf + 4][nf], 0, 0, 0);
        __builtin_amdgcn_s_setprio(0);
    }

    // ==== epilogue: value store + fused per-chunk phasor sums ====
    const int bb = m0 >> 12;                 // batch (4096 rows/batch, 256 | 4096)
    const int lb = (m0 & (SEQ - 1)) + wr;    // first in-batch row of this wave-half
    float csr[2][4][4], csi[2][4][4];
#pragma unroll
    for (int h = 0; h < 2; ++h)
#pragma unroll
        for (int nf = 0; nf < 4; ++nf)
#pragma unroll
            for (int j = 0; j < 4; ++j) { csr[h][nf][j] = 0.f; csi[h][nf][j] = 0.f; }

#pragma unroll
    for (int mf = 0; mf < 8; ++mf) {
        const int l    = lb + mf * 16 + rl;          // in-batch seq position
        const int grow = m0 + wr + mf * 16 + rl;
        const int half = mf >> 2;
#pragma unroll
        for (int nf = 0; nf < 4; ++nf) {
            const int gcol0 = n0 + wc + nf * 16 + rh * 4;
            f32x4 pp = *(const f32x4*)(ph + (size_t)l * DIM + gcol0);
            unsigned short os[4];
#pragma unroll
            for (int j = 0; j < 4; ++j) {
                float v = acc[mf][nf][j] + bv4[nf][j];
                float s, cn;
                __sincosf(pp[j], &s, &cn);
                csr[half][nf][j] += v * cn;
                csi[half][nf][j] += v * s;
                os[j] = f2bf(v);
            }
            ushort4 o; o.x = os[0]; o.y = os[1]; o.z = os[2]; o.w = os[3];
            *(ushort4*)(V + (size_t)grow * DIM + gcol0) = o;
        }
    }
    // reduce over rl (16-lane groups sharing rh): masks 1,2,4,8 stay in-group
#pragma unroll
    for (int h = 0; h < 2; ++h)
#pragma unroll
        for (int nf = 0; nf < 4; ++nf)
#pragma unroll
            for (int j = 0; j < 4; ++j) {
                float r = csr[h][nf][j], im = csi[h][nf][j];
#pragma unroll
                for (int mask = 1; mask < 16; mask <<= 1) {
                    r  += __shfl_xor(r,  mask, 64);
                    im += __shfl_xor(im, mask, 64);
                }
                csr[h][nf][j] = r; csi[h][nf][j] = im;
            }
    if (rl == 0) {
#pragma unroll
        for (int h = 0; h < 2; ++h) {
            const int c = (lb + h * 64) >> 6;        // chunk within batch
            const size_t base = ((size_t)bb * NC + c) * DIM;
#pragma unroll
            for (int nf = 0; nf < 4; ++nf) {
                const int gcol0 = n0 + wc + nf * 16 + rh * 4;
                *(float4*)(pr + base + gcol0) =
                    (float4){csr[h][nf][0], csr[h][nf][1], csr[h][nf][2], csr[h][nf][3]};
                *(float4*)(pi + base + gcol0) =
                    (float4){csi[h][nf][0], csi[h][nf][1], csi[h][nf][2], csi[h][nf][3]};
            }
        }
    }
}

// ---- pass B: exclusive scan of chunk partials over c ----
__global__ void passB_kernel(float* __restrict__ pr, float* __restrict__ pi) {
    int t = blockIdx.x * 256 + threadIdx.x;
    int bb = t >> 10;
    int e  = t & 1023;
    float r = 0.f, im = 0.f;
    for (int c = 0; c < NC; ++c) {
        size_t idx = ((size_t)bb * NC + c) * DIM + e;
        float tr = pr[idx], ti = pi[idx];
        pr[idx] = r; pi[idx] = im;
        r += tr; im += ti;
    }
}

// ---- pass C: running cumsum + retrieval + norm -> fp32 out ----
__global__ void passC_kernel(const unsigned short* __restrict__ val, const float* __restrict__ ph,
                             const float* __restrict__ pr, const float* __restrict__ pi,
                             float* __restrict__ out) {
    int t  = blockIdx.x * 256 + threadIdx.x;
    int c  = blockIdx.y;
    int bb = blockIdx.z;
    size_t base = ((size_t)bb * SEQ + (size_t)c * CL) * (DIM / 2) + t;
    const ushort2* v = (const ushort2*)val + base;
    const float2*  p = (const float2*)ph + (size_t)c * CL * (DIM / 2) + t;
    float2* o = (float2*)out + base;
    size_t pidx = ((size_t)bb * NC + c) * DIM + 2 * t;
    float ar0 = pr[pidx], ar1 = pr[pidx + 1];
    float ai0 = pi[pidx], ai1 = pi[pidx + 1];
    const int l0 = c * CL;
    for (int l = 0; l < CL; ++l) {
        ushort2 vv = v[(size_t)l * (DIM / 2)];
        float2  pp = p[(size_t)l * (DIM / 2)];
        float v0 = bf2f(vv.x), v1 = bf2f(vv.y);
        float s0, c0, s1, c1;
        __sincosf(pp.x, &s0, &c0);
        __sincosf(pp.y, &s1, &c1);
        ar0 += v0 * c0; ai0 += v0 * s0;
        ar1 += v1 * c1; ai1 += v1 * s1;
        float rn = rsqrtf((float)(l0 + l + 1));
        float2 ov;
        ov.x = (ar0 * c0 + ai0 * s0) * rn;
        ov.y = (ar1 * c1 + ai1 * s1) * rn;
        o[(size_t)l * (DIM / 2)] = ov;
    }
}

extern "C" void kernel_launch(void* const* d_in, const int* in_sizes, int n_in,
                              void* d_out, int out_size, void* d_ws, size_t ws_size,
                              hipStream_t stream) {
    const float* x  = (const float*)d_in[0];
    const float* ph = (const float*)d_in[1];
    const float* W  = (const float*)d_in[2];
    const float* b  = (const float*)d_in[3];
    float* out = (float*)d_out;

    // ws: vb bf16 32MB | wb 2MB | pr 1MB | pi 1MB
    unsigned short* vb = (unsigned short*)d_ws;
    unsigned short* wb = vb + (size_t)MROWS * DIM;
    float* pr = (float*)(wb + (size_t)DIM * DIM);
    float* pi = pr + (size_t)NB * NC * DIM;

    (void)hipFuncSetAttribute((const void*)gemm_kernel,
                              hipFuncAttributeMaxDynamicSharedMemorySize, GEMM_LDS);

    // 1) convert W only (x-conversion fused into GEMM LDS pipeline)
    convertW_kernel<<<DIM * DIM / 4 / 256, 256, 0, stream>>>(W, wb);
    // 2) GEMM + fused chunk-sum pass -> vb, pr, pi
    {
        dim3 grid(MROWS / BM, DIM / BN);
        gemm_kernel<<<grid, 512, GEMM_LDS, stream>>>(x, wb, b, ph, vb, pr, pi);
    }
    // 3) scan partials
    passB_kernel<<<16, 256, 0, stream>>>(pr, pi);
    // 4) final cumsum + retrieve + norm -> fp32 d_out
    {
        dim3 grid(DIM / 512, NC, NB);
        passC_kernel<<<grid, 256, 0, stream>>>(vb, ph, pr, pi, out);
    }
}

// Round 11
// 83.788 us; speedup vs baseline: 1.2236x; 1.0238x over previous
//
#include <hip/hip_runtime.h>
#include <hip/hip_bf16.h>

#define DIM 1024
#define SEQ 4096
#define NB 4
#define MROWS (NB * SEQ)   // 16384
#define NC 64              // chunks per sequence
#define CL (SEQ / NC)      // 64 L-positions per chunk

// GEMM tiling: 256x256 tile, BK=32, 3 LDS slots (A fp32 32KB + B bf16 16KB each)
#define BM 256
#define BN 256
#define BK 32
#define NTK 32                   // K-tiles: 1024/32
#define SLOTB 49152              // 48 KB per slot
#define GEMM_LDS (3 * SLOTB)     // 144 KB

typedef __attribute__((ext_vector_type(8))) short bf16x8;
typedef __attribute__((ext_vector_type(4))) float f32x4;

static __device__ __forceinline__ unsigned short f2bf(float f) {
    union { float f; unsigned u; } v; v.f = f;
    unsigned r = v.u + 0x7FFF + ((v.u >> 16) & 1);
    return (unsigned short)(r >> 16);
}

static __device__ __forceinline__ float bf2f(unsigned short h) {
    union { unsigned u; float f; } v; v.u = ((unsigned)h) << 16;
    return v.f;
}

// v_cvt_pk_bf16_f32: RNE, lo=bf16(a) in bits[15:0], hi=bf16(b) in bits[31:16]
static __device__ __forceinline__ unsigned cvtpk(float a, float b) {
    unsigned r;
    asm("v_cvt_pk_bf16_f32 %0, %1, %2" : "=v"(r) : "v"(a), "v"(b));
    return r;
}

static __device__ __forceinline__ void gload_lds16(const void* g, void* l) {
    __builtin_amdgcn_global_load_lds((const __attribute__((address_space(1))) void*)g,
                                     (__attribute__((address_space(3))) void*)l, 16, 0, 0);
}

// DPP butterfly add over the 16-lane row: x += dpp(x) for xor-distance d.
// quad_perm[1,0,3,2]=0xB1 (xor1), quad_perm[2,3,0,1]=0x4E (xor2),
// row_half_mirror=0x141 (xor4), row_mirror=0x140 (xor8). Full-rate VALU,
// no LDS pipe (replaces __shfl_xor's ds_swizzle lowering).
template<int CTRL>
static __device__ __forceinline__ float dppadd(float x) {
    int y = __builtin_amdgcn_update_dpp(0, __float_as_int(x), CTRL, 0xf, 0xf, true);
    return x + __int_as_float(y);
}
static __device__ __forceinline__ float rowreduce16(float x) {
    x = dppadd<0xB1>(x);
    x = dppadd<0x4E>(x);
    x = dppadd<0x141>(x);
    x = dppadd<0x140>(x);
    return x;
}

// ---- convert W fp32 -> bf16 (tiny) ----
__global__ void convertW_kernel(const float* __restrict__ W, unsigned short* __restrict__ wb) {
    int t = blockIdx.x * 256 + threadIdx.x;
    float4 v = ((const float4*)W)[t];
    ushort4 o;
    o.x = f2bf(v.x); o.y = f2bf(v.y); o.z = f2bf(v.z); o.w = f2bf(v.w);
    ((ushort4*)wb)[t] = o;
}

// Stage A K-tile (256 rows x 32 cols fp32 = 32 KB) of tile kt into slot.
// LDS rows 128B = 8 chunks of 16B, stored slot s holds global chunk s^(row&7).
static __device__ __forceinline__ void stage_Af32(const float* __restrict__ srcBase, char* smem,
                                                  int slot, int kt, int w, int lane) {
#pragma unroll
    for (int j = 0; j < 4; ++j) {
        const float* g = srcBase + (size_t)j * 8 * DIM + kt * BK;
        char* l = smem + (size_t)slot * SLOTB + (w * 4 + j) * 1024 + lane * 16;
        gload_lds16(g, l);
    }
}

// Stage B K-tile (256 rows x 32 cols bf16 = 16 KB) into slot at offset 32KB.
static __device__ __forceinline__ void stage_B16(const unsigned short* __restrict__ srcBase, char* smem,
                                                 int slot, int kt, int w, int lane) {
#pragma unroll
    for (int r = 0; r < 2; ++r) {
        const unsigned short* g = srcBase + (size_t)r * 128 * DIM + kt * BK;
        char* l = smem + (size_t)slot * SLOTB + 32768 + (r * 128 + w * 16) * 64 + lane * 16;
        gload_lds16(g, l);
    }
}

// ---- GEMM + fused passA: V = bf16(X@W^T + b); pr/pi[b][c][e] = per-chunk sums ----
__global__ __launch_bounds__(512, 2) void gemm_kernel(const float* __restrict__ X,
                                                      const unsigned short* __restrict__ Bm,
                                                      const float* __restrict__ bias,
                                                      const float* __restrict__ ph,
                                                      unsigned short* __restrict__ V,
                                                      float* __restrict__ pr,
                                                      float* __restrict__ pi) {
    extern __shared__ char smem[];
    const int tid  = threadIdx.x;
    const int lane = tid & 63;
    const int w    = tid >> 6;           // wave 0..7
    const int wr   = (w >> 2) * 128;     // wave row offset (M)
    const int wc   = (w & 3) * 64;       // wave col offset (N)
    const int rl   = lane & 15;
    const int rh   = lane >> 4;
    const int m0   = blockIdx.x * BM;
    const int n0   = blockIdx.y * BN;

    // staging source bases (chunk XOR folded into per-lane global src)
    const float* srcA = X + (size_t)(m0 + w * 32 + (lane >> 3)) * DIM + ((lane & 7) ^ (lane >> 3)) * 4;
    const unsigned short* srcB = Bm + (size_t)(n0 + w * 16 + (lane >> 2)) * DIM
                               + (((lane & 3) ^ ((lane >> 3) & 3)) * 8);

    // read-side offsets
    const int swzB = (rh ^ ((rl >> 1) & 3)) * 16;
    const int aoff0 = (wr + rl) * 128 + (((rh * 2 + 0) ^ (rl & 7)) * 16);
    const int aoff1 = (wr + rl) * 128 + (((rh * 2 + 1) ^ (rl & 7)) * 16);

    f32x4 acc[8][4];
#pragma unroll
    for (int m = 0; m < 8; ++m)
#pragma unroll
        for (int n = 0; n < 4; ++n)
            acc[m][n] = (f32x4){0.f, 0.f, 0.f, 0.f};

    f32x4 bv4[4];
#pragma unroll
    for (int nf = 0; nf < 4; ++nf)
        bv4[nf] = *(const f32x4*)(bias + n0 + wc + nf * 16 + rh * 4);

    // prologue: stage tiles 0 (slot0) and 1 (slot1)
    stage_Af32(srcA, smem, 0, 0, w, lane);
    stage_B16 (srcB, smem, 0, 0, w, lane);
    stage_Af32(srcA, smem, 1, 1, w, lane);
    stage_B16 (srcB, smem, 1, 1, w, lane);

#pragma unroll 1
    for (int t = 0; t < NTK; ++t) {
        asm volatile("s_waitcnt vmcnt(6)" ::: "memory");
        __builtin_amdgcn_s_barrier();
        const int sc = t % 3;
        const int ss = (t + 2) % 3;
        const int kn = (t + 2) & (NTK - 1);
        const char* sb = smem + (size_t)sc * SLOTB;

        bf16x8 bfr[4];
#pragma unroll
        for (int nf = 0; nf < 4; ++nf)
            bfr[nf] = *(const bf16x8*)(sb + 32768 + (wc + nf * 16 + rl) * 64 + swzB);

        bf16x8 af[4];
#pragma unroll
        for (int mf = 0; mf < 4; ++mf) {
            f32x4 q0 = *(const f32x4*)(sb + mf * 2048 + aoff0);
            f32x4 q1 = *(const f32x4*)(sb + mf * 2048 + aoff1);
            union { unsigned u[4]; bf16x8 v; } cv;
            cv.u[0] = cvtpk(q0[0], q0[1]); cv.u[1] = cvtpk(q0[2], q0[3]);
            cv.u[2] = cvtpk(q1[0], q1[1]); cv.u[3] = cvtpk(q1[2], q1[3]);
            af[mf] = cv.v;
        }
        stage_Af32(srcA, smem, ss, kn, w, lane);
        __builtin_amdgcn_s_setprio(1);
#pragma unroll
        for (int mf = 0; mf < 4; ++mf)
#pragma unroll
            for (int nf = 0; nf < 4; ++nf)
                acc[mf][nf] = __builtin_amdgcn_mfma_f32_16x16x32_bf16(bfr[nf], af[mf], acc[mf][nf], 0, 0, 0);
        __builtin_amdgcn_s_setprio(0);

#pragma unroll
        for (int mf = 0; mf < 4; ++mf) {
            f32x4 q0 = *(const f32x4*)(sb + (mf + 4) * 2048 + aoff0);
            f32x4 q1 = *(const f32x4*)(sb + (mf + 4) * 2048 + aoff1);
            union { unsigned u[4]; bf16x8 v; } cv;
            cv.u[0] = cvtpk(q0[0], q0[1]); cv.u[1] = cvtpk(q0[2], q0[3]);
            cv.u[2] = cvtpk(q1[0], q1[1]); cv.u[3] = cvtpk(q1[2], q1[3]);
            af[mf] = cv.v;
        }
        stage_B16(srcB, smem, ss, kn, w, lane);
        __builtin_amdgcn_s_setprio(1);
#pragma unroll
        for (int mf = 0; mf < 4; ++mf)
#pragma unroll
            for (int nf = 0; nf < 4; ++nf)
                acc[mf + 4][nf] = __builtin_amdgcn_mfma_f32_16x16x32_bf16(bfr[nf], af[mf], acc[mf + 4][nf], 0, 0, 0);
        __builtin_amdgcn_s_setprio(0);
    }

    // ==== epilogue: value store + fused per-chunk phasor sums ====
    const int bb = m0 >> 12;                 // batch (4096 rows/batch, 256 | 4096)
    const int lb = (m0 & (SEQ - 1)) + wr;    // first in-batch row of this wave-half
    float csr[2][4][4], csi[2][4][4];
#pragma unroll
    for (int h = 0; h < 2; ++h)
#pragma unroll
        for (int nf = 0; nf < 4; ++nf)
#pragma unroll
            for (int j = 0; j < 4; ++j) { csr[h][nf][j] = 0.f; csi[h][nf][j] = 0.f; }

#pragma unroll
    for (int mf = 0; mf < 8; ++mf) {
        const int l    = lb + mf * 16 + rl;          // in-batch seq position
        const int grow = m0 + wr + mf * 16 + rl;
        const int half = mf >> 2;
#pragma unroll
        for (int nf = 0; nf < 4; ++nf) {
            const int gcol0 = n0 + wc + nf * 16 + rh * 4;
            f32x4 pp = *(const f32x4*)(ph + (size_t)l * DIM + gcol0);
            unsigned short os[4];
#pragma unroll
            for (int j = 0; j < 4; ++j) {
                float v = acc[mf][nf][j] + bv4[nf][j];
                float s, cn;
                __sincosf(pp[j], &s, &cn);
                csr[half][nf][j] += v * cn;
                csi[half][nf][j] += v * s;
                os[j] = f2bf(v);
            }
            ushort4 o; o.x = os[0]; o.y = os[1]; o.z = os[2]; o.w = os[3];
            *(ushort4*)(V + (size_t)grow * DIM + gcol0) = o;
        }
    }
    // reduce over rl (16-lane DPP rows; rh groups ARE the DPP rows)
#pragma unroll
    for (int h = 0; h < 2; ++h)
#pragma unroll
        for (int nf = 0; nf < 4; ++nf)
#pragma unroll
            for (int j = 0; j < 4; ++j) {
                csr[h][nf][j] = rowreduce16(csr[h][nf][j]);
                csi[h][nf][j] = rowreduce16(csi[h][nf][j]);
            }
    if (rl == 0) {
#pragma unroll
        for (int h = 0; h < 2; ++h) {
            const int c = (lb + h * 64) >> 6;        // chunk within batch
            const size_t base = ((size_t)bb * NC + c) * DIM;
#pragma unroll
            for (int nf = 0; nf < 4; ++nf) {
                const int gcol0 = n0 + wc + nf * 16 + rh * 4;
                *(float4*)(pr + base + gcol0) =
                    (float4){csr[h][nf][0], csr[h][nf][1], csr[h][nf][2], csr[h][nf][3]};
                *(float4*)(pi + base + gcol0) =
                    (float4){csi[h][nf][0], csi[h][nf][1], csi[h][nf][2], csi[h][nf][3]};
            }
        }
    }
}

// ---- pass B: exclusive scan of chunk partials over c ----
__global__ void passB_kernel(float* __restrict__ pr, float* __restrict__ pi) {
    int t = blockIdx.x * 256 + threadIdx.x;
    int bb = t >> 10;
    int e  = t & 1023;
    float r = 0.f, im = 0.f;
    for (int c = 0; c < NC; ++c) {
        size_t idx = ((size_t)bb * NC + c) * DIM + e;
        float tr = pr[idx], ti = pi[idx];
        pr[idx] = r; pi[idx] = im;
        r += tr; im += ti;
    }
}

// ---- pass C: running cumsum + retrieval + norm -> fp32 out ----
__global__ void passC_kernel(const unsigned short* __restrict__ val, const float* __restrict__ ph,
                             const float* __restrict__ pr, const float* __restrict__ pi,
                             float* __restrict__ out) {
    int t  = blockIdx.x * 256 + threadIdx.x;
    int c  = blockIdx.y;
    int bb = blockIdx.z;
    size_t base = ((size_t)bb * SEQ + (size_t)c * CL) * (DIM / 2) + t;
    const ushort2* v = (const ushort2*)val + base;
    const float2*  p = (const float2*)ph + (size_t)c * CL * (DIM / 2) + t;
    float2* o = (float2*)out + base;
    size_t pidx = ((size_t)bb * NC + c) * DIM + 2 * t;
    float ar0 = pr[pidx], ar1 = pr[pidx + 1];
    float ai0 = pi[pidx], ai1 = pi[pidx + 1];
    const int l0 = c * CL;
    for (int l = 0; l < CL; ++l) {
        ushort2 vv = v[(size_t)l * (DIM / 2)];
        float2  pp = p[(size_t)l * (DIM / 2)];
        float v0 = bf2f(vv.x), v1 = bf2f(vv.y);
        float s0, c0, s1, c1;
        __sincosf(pp.x, &s0, &c0);
        __sincosf(pp.y, &s1, &c1);
        ar0 += v0 * c0; ai0 += v0 * s0;
        ar1 += v1 * c1; ai1 += v1 * s1;
        float rn = rsqrtf((float)(l0 + l + 1));
        float2 ov;
        ov.x = (ar0 * c0 + ai0 * s0) * rn;
        ov.y = (ar1 * c1 + ai1 * s1) * rn;
        o[(size_t)l * (DIM / 2)] = ov;
    }
}

extern "C" void kernel_launch(void* const* d_in, const int* in_sizes, int n_in,
                              void* d_out, int out_size, void* d_ws, size_t ws_size,
                              hipStream_t stream) {
    const float* x  = (const float*)d_in[0];
    const float* ph = (const float*)d_in[1];
    const float* W  = (const float*)d_in[2];
    const float* b  = (const float*)d_in[3];
    float* out = (float*)d_out;

    // ws: vb bf16 32MB | wb 2MB | pr 1MB | pi 1MB
    unsigned short* vb = (unsigned short*)d_ws;
    unsigned short* wb = vb + (size_t)MROWS * DIM;
    float* pr = (float*)(wb + (size_t)DIM * DIM);
    float* pi = pr + (size_t)NB * NC * DIM;

    (void)hipFuncSetAttribute((const void*)gemm_kernel,
                              hipFuncAttributeMaxDynamicSharedMemorySize, GEMM_LDS);

    // 1) convert W only (x-conversion fused into GEMM LDS pipeline)
    convertW_kernel<<<DIM * DIM / 4 / 256, 256, 0, stream>>>(W, wb);
    // 2) GEMM + fused chunk-sum pass -> vb, pr, pi
    {
        dim3 grid(MROWS / BM, DIM / BN);
        gemm_kernel<<<grid, 512, GEMM_LDS, stream>>>(x, wb, b, ph, vb, pr, pi);
    }
    // 3) scan partials
    passB_kernel<<<16, 256, 0, stream>>>(pr, pi);
    // 4) final cumsum + retrieve + norm -> fp32 d_out
    {
        dim3 grid(DIM / 512, NC, NB);
        passC_kernel<<<grid, 256, 0, stream>>>(vb, ph, pr, pi, out);
    }
}